// Round 1
// baseline (8720.882 us; speedup 1.0000x reference)
//
#include <hip/hip_runtime.h>
#include <math.h>

#define NH 16
#define HD 64
#define SEQ 1024
#define NB 8
#define CH 1024
#define TD 256

// ---------------- kernel 1: time projection ----------------
// tqkv[b][c] = sum_t time_emb[b][t] * W_time[t][c] + b_time[c]
__global__ __launch_bounds__(256) void time_proj_kernel(
    const float* __restrict__ time_emb, const float* __restrict__ W_time,
    const float* __restrict__ b_time, float* __restrict__ tqkv) {
  int idx = blockIdx.x * 256 + threadIdx.x;  // 8*3072 = 24576
  if (idx >= NB * 3072) return;
  int b = idx / 3072, c = idx % 3072;
  float s = b_time[c];
  for (int t = 0; t < TD; ++t) s += time_emb[b * TD + t] * W_time[t * 3072 + c];
  tqkv[idx] = s;
}

// ---------------- kernel 2: QKV GEMM + scatter ----------------
// X (8192 x 1024) @ W_qkv (1024 x 3072) + b_qkv + tqkv -> q/k/v (B*H, N, D)
__global__ __launch_bounds__(256) void qkv_gemm_kernel(
    const float* __restrict__ X, const float* __restrict__ W,
    const float* __restrict__ bqkv, const float* __restrict__ tqkv,
    float* __restrict__ qb, float* __restrict__ kb, float* __restrict__ vb) {
  __shared__ float As[16][65];
  __shared__ float Bs[16][65];
  const int m0 = blockIdx.x * 64;
  const int n0 = blockIdx.y * 64;
  const int tid = threadIdx.x;
  const int tx = tid & 15, ty = tid >> 4;
  float acc[4][4] = {};
  for (int k0 = 0; k0 < 1024; k0 += 16) {
#pragma unroll
    for (int i = 0; i < 4; ++i) {
      int idx = tid + 256 * i;
      int mr = idx >> 4, kk = idx & 15;
      As[kk][mr] = X[(size_t)(m0 + mr) * 1024 + k0 + kk];
    }
#pragma unroll
    for (int i = 0; i < 4; ++i) {
      int idx = tid + 256 * i;
      int kr = idx >> 6, nc = idx & 63;
      Bs[kr][nc] = W[(size_t)(k0 + kr) * 3072 + n0 + nc];
    }
    __syncthreads();
#pragma unroll
    for (int kk = 0; kk < 16; ++kk) {
      float a[4], bb[4];
#pragma unroll
      for (int i = 0; i < 4; ++i) a[i] = As[kk][ty + 16 * i];
#pragma unroll
      for (int j = 0; j < 4; ++j) bb[j] = Bs[kk][tx + 16 * j];
#pragma unroll
      for (int i = 0; i < 4; ++i)
#pragma unroll
        for (int j = 0; j < 4; ++j) acc[i][j] += a[i] * bb[j];
    }
    __syncthreads();
  }
#pragma unroll
  for (int i = 0; i < 4; ++i) {
    int m = m0 + ty + 16 * i;
    int b = m >> 10, nn = m & 1023;
#pragma unroll
    for (int j = 0; j < 4; ++j) {
      int c = n0 + tx + 16 * j;
      float val = acc[i][j] + bqkv[c] + tqkv[b * 3072 + c];
      int which = c >> 10, cc = c & 1023;
      int hh = cc >> 6, d = cc & 63;
      float* dst = (which == 0) ? qb : (which == 1) ? kb : vb;
      dst[(((size_t)(b * NH + hh)) * SEQ + nn) * HD + d] = val;
    }
  }
}

// ---------------- kernel 3: flash attention with skewed rel ----------------
// scores[n][m] = scale*q_n.k_m + R(n,m)
// R: m<=n -> q_n.Er[1023+m-n]; m==n+1 -> 0; m>=n+2 -> q_{n+1}.Er[m-n-2]
__global__ __launch_bounds__(256) void attn_kernel(
    const float* __restrict__ qb, const float* __restrict__ kb,
    const float* __restrict__ vb, const float* __restrict__ Er,
    float* __restrict__ attn_out) {
  const int bh = blockIdx.y;       // 0..127
  const int n0 = blockIdx.x * 16;  // q-row tile
  const int b = bh >> 4, h = bh & 15;
  const int tid = threadIdx.x;
  __shared__ float Qs[17][64];
  __shared__ float Ks[64][65];
  __shared__ float Vs[64][65];
  __shared__ float S[16][65];
  __shared__ float mrow[16], lrow[16], corr[16];

  const float* qh = qb + (size_t)bh * SEQ * HD;
  const float* kh = kb + (size_t)bh * SEQ * HD;
  const float* vh = vb + (size_t)bh * SEQ * HD;

  for (int idx = tid; idx < 17 * 64; idx += 256) {
    int r = idx >> 6, d = idx & 63;
    int n = n0 + r;
    Qs[r][d] = (n < SEQ) ? qh[(size_t)n * HD + d] : 0.f;
  }
  if (tid < 16) { mrow[tid] = -INFINITY; lrow[tid] = 0.f; }

  float acc[4] = {0.f, 0.f, 0.f, 0.f};
  const int dcol = tid & 63;
  const int rbase = (tid >> 6) * 4;
  const float scale = 0.125f;

  for (int m0 = 0; m0 < SEQ; m0 += 64) {
    __syncthreads();
#pragma unroll
    for (int i = 0; i < 16; ++i) {
      int idx = tid + 256 * i;
      int j = idx >> 6, d = idx & 63;
      Ks[j][d] = kh[(size_t)(m0 + j) * HD + d];
      Vs[j][d] = vh[(size_t)(m0 + j) * HD + d];
    }
    __syncthreads();
#pragma unroll
    for (int i = 0; i < 4; ++i) {
      int r = rbase + i;
      int n = n0 + r;
      int m = m0 + dcol;
      float qk = 0.f;
#pragma unroll
      for (int d = 0; d < 64; ++d) qk += Qs[r][d] * Ks[dcol][d];
      float rel = 0.f;
      if (m <= n) {
        const float* er = Er + (size_t)(1023 + m - n) * HD;
        for (int d = 0; d < 64; ++d) rel += Qs[r][d] * er[d];
      } else if (m >= n + 2) {
        const float* er = Er + (size_t)(m - n - 2) * HD;
        for (int d = 0; d < 64; ++d) rel += Qs[r + 1][d] * er[d];
      }
      S[r][dcol] = qk * scale + rel;
    }
    __syncthreads();
    if (tid < 16) {
      float mx = mrow[tid];
      float rmax = -INFINITY;
      for (int c2 = 0; c2 < 64; ++c2) rmax = fmaxf(rmax, S[tid][c2]);
      float mnew = fmaxf(mx, rmax);
      float cr = expf(mx - mnew);
      float rs = 0.f;
      for (int c2 = 0; c2 < 64; ++c2) {
        float p = expf(S[tid][c2] - mnew);
        S[tid][c2] = p;
        rs += p;
      }
      lrow[tid] = lrow[tid] * cr + rs;
      mrow[tid] = mnew;
      corr[tid] = cr;
    }
    __syncthreads();
#pragma unroll
    for (int i = 0; i < 4; ++i) {
      int r = rbase + i;
      float s2 = 0.f;
#pragma unroll
      for (int j = 0; j < 64; ++j) s2 += S[r][j] * Vs[j][dcol];
      acc[i] = acc[i] * corr[r] + s2;
    }
  }
#pragma unroll
  for (int i = 0; i < 4; ++i) {
    int r = rbase + i;
    int n = n0 + r;
    attn_out[((size_t)(b * SEQ + n)) * CH + h * HD + dcol] = acc[i] / lrow[r];
  }
}

// ---------------- kernel 4: output projection ----------------
// A (8192 x 1024) @ W_out (1024 x 1024) + b_out -> out
__global__ __launch_bounds__(256) void out_gemm_kernel(
    const float* __restrict__ A, const float* __restrict__ W,
    const float* __restrict__ bias, float* __restrict__ out) {
  __shared__ float As[16][65];
  __shared__ float Bs[16][65];
  const int m0 = blockIdx.x * 64;
  const int n0 = blockIdx.y * 64;
  const int tid = threadIdx.x;
  const int tx = tid & 15, ty = tid >> 4;
  float acc[4][4] = {};
  for (int k0 = 0; k0 < 1024; k0 += 16) {
#pragma unroll
    for (int i = 0; i < 4; ++i) {
      int idx = tid + 256 * i;
      int mr = idx >> 4, kk = idx & 15;
      As[kk][mr] = A[(size_t)(m0 + mr) * 1024 + k0 + kk];
    }
#pragma unroll
    for (int i = 0; i < 4; ++i) {
      int idx = tid + 256 * i;
      int kr = idx >> 6, nc = idx & 63;
      Bs[kr][nc] = W[(size_t)(k0 + kr) * 1024 + n0 + nc];
    }
    __syncthreads();
#pragma unroll
    for (int kk = 0; kk < 16; ++kk) {
      float a[4], bb[4];
#pragma unroll
      for (int i = 0; i < 4; ++i) a[i] = As[kk][ty + 16 * i];
#pragma unroll
      for (int j = 0; j < 4; ++j) bb[j] = Bs[kk][tx + 16 * j];
#pragma unroll
      for (int i = 0; i < 4; ++i)
#pragma unroll
        for (int j = 0; j < 4; ++j) acc[i][j] += a[i] * bb[j];
    }
    __syncthreads();
  }
#pragma unroll
  for (int i = 0; i < 4; ++i) {
    int m = m0 + ty + 16 * i;
#pragma unroll
    for (int j = 0; j < 4; ++j) {
      int c = n0 + tx + 16 * j;
      out[(size_t)m * 1024 + c] = acc[i][j] + bias[c];
    }
  }
}

extern "C" void kernel_launch(void* const* d_in, const int* in_sizes, int n_in,
                              void* d_out, int out_size, void* d_ws, size_t ws_size,
                              hipStream_t stream) {
  const float* x        = (const float*)d_in[0];
  const float* time_emb = (const float*)d_in[1];
  const float* W_qkv    = (const float*)d_in[2];
  const float* b_qkv    = (const float*)d_in[3];
  const float* W_time   = (const float*)d_in[4];
  const float* b_time   = (const float*)d_in[5];
  const float* W_out    = (const float*)d_in[6];
  const float* b_out    = (const float*)d_in[7];
  const float* Er       = (const float*)d_in[8];
  float* out = (float*)d_out;

  float* ws = (float*)d_ws;
  float* tqkv = ws;                         // 24576
  float* qb = tqkv + 24576;                 // 8388608 each
  float* kb = qb + (size_t)8388608;
  float* vb = kb + (size_t)8388608;
  float* attn_out = vb + (size_t)8388608;   // 8388608

  time_proj_kernel<<<96, 256, 0, stream>>>(time_emb, W_time, b_time, tqkv);
  qkv_gemm_kernel<<<dim3(128, 48), 256, 0, stream>>>(x, W_qkv, b_qkv, tqkv,
                                                     qb, kb, vb);
  attn_kernel<<<dim3(64, 128), 256, 0, stream>>>(qb, kb, vb, Er, attn_out);
  out_gemm_kernel<<<dim3(128, 16), 256, 0, stream>>>(attn_out, W_out, b_out, out);
}

// Round 2
// 1532.485 us; speedup vs baseline: 5.6907x; 5.6907x over previous
//
#include <hip/hip_runtime.h>
#include <math.h>

typedef __attribute__((ext_vector_type(8))) short short8;
typedef __attribute__((ext_vector_type(4))) float f32x4;

#define NH 16
#define HD 64
#define SEQ 1024
#define NB 8
#define CH 1024
#define TD 256
#define SLAB_BH 32

__device__ __forceinline__ unsigned short f2bf(float f) {
  union { float f; unsigned int u; } v; v.f = f;
  unsigned int r = v.u + 0x7FFFu + ((v.u >> 16) & 1u);
  return (unsigned short)(r >> 16);
}
__device__ __forceinline__ float bf2f(unsigned short s) {
  union { unsigned int u; float f; } v; v.u = ((unsigned int)s) << 16;
  return v.f;
}

// ---------------- time projection (fp32) ----------------
__global__ __launch_bounds__(256) void time_proj_kernel(
    const float* __restrict__ time_emb, const float* __restrict__ W_time,
    const float* __restrict__ b_time, float* __restrict__ tqkv) {
  int idx = blockIdx.x * 256 + threadIdx.x;
  if (idx >= NB * 3072) return;
  int b = idx / 3072, c = idx % 3072;
  float s = b_time[c];
  for (int t = 0; t < TD; ++t) s += time_emb[b * TD + t] * W_time[t * 3072 + c];
  tqkv[idx] = s;
}

// ---------------- Er fp32 -> bf16 ----------------
__global__ __launch_bounds__(256) void er_convert_kernel(
    const float* __restrict__ Er, unsigned short* __restrict__ Er_bf) {
  int i = blockIdx.x * 256 + threadIdx.x;
  if (i < SEQ * HD) Er_bf[i] = f2bf(Er[i]);
}

// ---------------- QKV GEMM (fp32 compute, bf16 out) ----------------
__global__ __launch_bounds__(256) void qkv_gemm_kernel(
    const float* __restrict__ X, const float* __restrict__ W,
    const float* __restrict__ bqkv, const float* __restrict__ tqkv,
    unsigned short* __restrict__ qb, unsigned short* __restrict__ kb,
    unsigned short* __restrict__ vb) {
  __shared__ float As[16][65];
  __shared__ float Bs[16][65];
  const int m0 = blockIdx.x * 64;
  const int n0 = blockIdx.y * 64;
  const int tid = threadIdx.x;
  const int tx = tid & 15, ty = tid >> 4;
  float acc[4][4] = {};
  for (int k0 = 0; k0 < 1024; k0 += 16) {
#pragma unroll
    for (int i = 0; i < 4; ++i) {
      int idx = tid + 256 * i;
      int mr = idx >> 4, kk = idx & 15;
      As[kk][mr] = X[(size_t)(m0 + mr) * 1024 + k0 + kk];
    }
#pragma unroll
    for (int i = 0; i < 4; ++i) {
      int idx = tid + 256 * i;
      int kr = idx >> 6, nc = idx & 63;
      Bs[kr][nc] = W[(size_t)(k0 + kr) * 3072 + n0 + nc];
    }
    __syncthreads();
#pragma unroll
    for (int kk = 0; kk < 16; ++kk) {
      float a[4], bb[4];
#pragma unroll
      for (int i = 0; i < 4; ++i) a[i] = As[kk][ty + 16 * i];
#pragma unroll
      for (int j = 0; j < 4; ++j) bb[j] = Bs[kk][tx + 16 * j];
#pragma unroll
      for (int i = 0; i < 4; ++i)
#pragma unroll
        for (int j = 0; j < 4; ++j) acc[i][j] += a[i] * bb[j];
    }
    __syncthreads();
  }
#pragma unroll
  for (int i = 0; i < 4; ++i) {
    int m = m0 + ty + 16 * i;
    int b = m >> 10, nn = m & 1023;
#pragma unroll
    for (int j = 0; j < 4; ++j) {
      int c = n0 + tx + 16 * j;
      float val = acc[i][j] + bqkv[c] + tqkv[b * 3072 + c];
      int which = c >> 10, cc = c & 1023;
      int hh = cc >> 6, d = cc & 63;
      unsigned short* dst = (which == 0) ? qb : (which == 1) ? kb : vb;
      dst[(((size_t)(b * NH + hh)) * SEQ + nn) * HD + d] = f2bf(val);
    }
  }
}

// ---------------- G GEMM with skew remap store ----------------
// G[n][j] = q_n . Er[j]; store to Gsk[n][j+n-1023] (j>=1023-n) else Gsk[n-1][j+n+1]
__global__ __launch_bounds__(256) void g_gemm_kernel(
    const unsigned short* __restrict__ qb, int bh_base,
    const unsigned short* __restrict__ Er_bf,
    unsigned short* __restrict__ Gsk) {
  const int n0 = blockIdx.x * 64, j0 = blockIdx.y * 64, bhl = blockIdx.z;
  const int bh = bh_base + bhl;
  const int tid = threadIdx.x, lane = tid & 63, wq = tid >> 6;
  const int grp = lane >> 4, col = lane & 15;
  short8 aq[2];
  const int nrow = n0 + wq * 16 + col;
#pragma unroll
  for (int dc = 0; dc < 2; ++dc)
    aq[dc] = *(const short8*)(qb + ((size_t)(bh * SEQ + nrow)) * HD + dc * 32 + grp * 8);
  f32x4 acc[4];
#pragma unroll
  for (int mc = 0; mc < 4; ++mc) acc[mc] = (f32x4){0.f, 0.f, 0.f, 0.f};
#pragma unroll
  for (int mc = 0; mc < 4; ++mc)
#pragma unroll
    for (int dc = 0; dc < 2; ++dc) {
      short8 bfrag = *(const short8*)(Er_bf + (size_t)(j0 + mc * 16 + col) * HD + dc * 32 + grp * 8);
      acc[mc] = __builtin_amdgcn_mfma_f32_16x16x32_bf16(aq[dc], bfrag, acc[mc], 0, 0, 0);
    }
#pragma unroll
  for (int mc = 0; mc < 4; ++mc)
#pragma unroll
    for (int r = 0; r < 4; ++r) {
      int n = n0 + wq * 16 + grp * 4 + r;
      int j = j0 + mc * 16 + col;
      float val = acc[mc][r];
      int tr, tm;
      if (j >= 1023 - n) { tr = n; tm = j + n - 1023; }
      else               { tr = n - 1; tm = j + n + 1; }
      if (tr >= 0) Gsk[((size_t)(bhl * SEQ + tr) << 10) + tm] = f2bf(val);
    }
}

__global__ __launch_bounds__(256) void diag_zero_kernel(unsigned short* __restrict__ Gsk) {
  int i = blockIdx.x * 256 + threadIdx.x;
  if (i >= SLAB_BH * 1023) return;
  int bhl = i / 1023, n = i % 1023;
  Gsk[((size_t)(bhl * SEQ + n) << 10) + n + 1] = 0;
}

// ---------------- flash attention, bf16 MFMA ----------------
__global__ __launch_bounds__(256) void attn_kernel(
    const unsigned short* __restrict__ qb, const unsigned short* __restrict__ kb,
    const unsigned short* __restrict__ vb, const unsigned short* __restrict__ Gsk,
    unsigned short* __restrict__ attn_o, int bh_base) {
  __shared__ __align__(16) unsigned short Ks[64][72];
  __shared__ __align__(16) unsigned short Vt[64][72];
  __shared__ __align__(16) unsigned short Pw[4][16][72];
  const int n0 = blockIdx.x * 64;
  const int bhl = blockIdx.y;
  const int bh = bh_base + bhl;
  const int b = bh >> 4, h = bh & 15;
  const int tid = threadIdx.x, lane = tid & 63, wq = tid >> 6;
  const int grp = lane >> 4, col = lane & 15;
  const int n0w = n0 + wq * 16;

  short8 aq[2];
#pragma unroll
  for (int dc = 0; dc < 2; ++dc)
    aq[dc] = *(const short8*)(qb + ((size_t)(bh * SEQ + n0w + col)) * HD + dc * 32 + grp * 8);

  f32x4 acco[4];
#pragma unroll
  for (int oc = 0; oc < 4; ++oc) acco[oc] = (f32x4){0.f, 0.f, 0.f, 0.f};
  float mrun[4], lrun[4];
#pragma unroll
  for (int r = 0; r < 4; ++r) { mrun[r] = -INFINITY; lrun[r] = 0.f; }

  // prefetched rel values (one k-tile ahead)
  unsigned short gv[16];
  const size_t grow = ((size_t)(bhl * SEQ + n0w + grp * 4)) << 10;
#pragma unroll
  for (int r = 0; r < 4; ++r)
#pragma unroll
    for (int mc = 0; mc < 4; ++mc)
      gv[r * 4 + mc] = Gsk[grow + ((size_t)r << 10) + mc * 16 + col];

  const float scale = 0.125f;
  const unsigned short* kbh = kb + (size_t)bh * SEQ * HD;
  const unsigned short* vbh = vb + (size_t)bh * SEQ * HD;

  for (int m0 = 0; m0 < SEQ; m0 += 64) {
    __syncthreads();
    // stage K rows and V^T
    {
      int rowa = tid >> 3;
      int d0 = (tid & 7) * 8;
#pragma unroll
      for (int it = 0; it < 2; ++it) {
        int m = rowa + it * 32;
        short8 kv = *(const short8*)(kbh + (size_t)(m0 + m) * HD + d0);
        *(short8*)&Ks[m][d0] = kv;
        short8 vv = *(const short8*)(vbh + (size_t)(m0 + m) * HD + d0);
#pragma unroll
        for (int e = 0; e < 8; ++e) Vt[d0 + e][m] = (unsigned short)vv[e];
      }
    }
    __syncthreads();
    // QK^T
    f32x4 acc[4];
#pragma unroll
    for (int mc = 0; mc < 4; ++mc) acc[mc] = (f32x4){0.f, 0.f, 0.f, 0.f};
#pragma unroll
    for (int mc = 0; mc < 4; ++mc)
#pragma unroll
      for (int dc = 0; dc < 2; ++dc) {
        short8 bk = *(const short8*)&Ks[mc * 16 + col][dc * 32 + grp * 8];
        acc[mc] = __builtin_amdgcn_mfma_f32_16x16x32_bf16(aq[dc], bk, acc[mc], 0, 0, 0);
      }
    // consume prefetched rel, issue next prefetch
    float gf[16];
#pragma unroll
    for (int i = 0; i < 16; ++i) gf[i] = bf2f(gv[i]);
    if (m0 + 64 < SEQ) {
#pragma unroll
      for (int r = 0; r < 4; ++r)
#pragma unroll
        for (int mc = 0; mc < 4; ++mc)
          gv[r * 4 + mc] = Gsk[grow + ((size_t)r << 10) + (m0 + 64) + mc * 16 + col];
    }
    // online softmax (wave-parallel, 16-lane column groups)
#pragma unroll
    for (int r = 0; r < 4; ++r) {
      float s[4];
#pragma unroll
      for (int mc = 0; mc < 4; ++mc) s[mc] = acc[mc][r] * scale + gf[r * 4 + mc];
      float mx = fmaxf(fmaxf(s[0], s[1]), fmaxf(s[2], s[3]));
#pragma unroll
      for (int off = 1; off < 16; off <<= 1) mx = fmaxf(mx, __shfl_xor(mx, off));
      float mnew = fmaxf(mrun[r], mx);
      float cr = __expf(mrun[r] - mnew);
      float ls = 0.f;
      float p[4];
#pragma unroll
      for (int mc = 0; mc < 4; ++mc) { p[mc] = __expf(s[mc] - mnew); ls += p[mc]; }
#pragma unroll
      for (int off = 1; off < 16; off <<= 1) ls += __shfl_xor(ls, off);
      lrun[r] = lrun[r] * cr + ls;
      mrun[r] = mnew;
#pragma unroll
      for (int oc = 0; oc < 4; ++oc) acco[oc][r] *= cr;
#pragma unroll
      for (int mc = 0; mc < 4; ++mc) Pw[wq][grp * 4 + r][mc * 16 + col] = f2bf(p[mc]);
    }
    // PV
    short8 ap[2];
#pragma unroll
    for (int kc = 0; kc < 2; ++kc)
      ap[kc] = *(const short8*)&Pw[wq][col][kc * 32 + grp * 8];
#pragma unroll
    for (int oc = 0; oc < 4; ++oc)
#pragma unroll
      for (int kc = 0; kc < 2; ++kc) {
        short8 bv = *(const short8*)&Vt[oc * 16 + col][kc * 32 + grp * 8];
        acco[oc] = __builtin_amdgcn_mfma_f32_16x16x32_bf16(ap[kc], bv, acco[oc], 0, 0, 0);
      }
  }
  // epilogue
#pragma unroll
  for (int oc = 0; oc < 4; ++oc)
#pragma unroll
    for (int r = 0; r < 4; ++r) {
      int n = n0w + grp * 4 + r;
      int d = oc * 16 + col;
      attn_o[((size_t)(b * SEQ + n)) * CH + h * HD + d] = f2bf(acco[oc][r] / lrun[r]);
    }
}

// ---------------- output projection (bf16 in, fp32 compute/out) ----------------
__global__ __launch_bounds__(256) void out_gemm_kernel(
    const unsigned short* __restrict__ A, const float* __restrict__ W,
    const float* __restrict__ bias, float* __restrict__ out) {
  __shared__ float As[16][65];
  __shared__ float Bs[16][65];
  const int m0 = blockIdx.x * 64;
  const int n0 = blockIdx.y * 64;
  const int tid = threadIdx.x;
  const int tx = tid & 15, ty = tid >> 4;
  float acc[4][4] = {};
  for (int k0 = 0; k0 < 1024; k0 += 16) {
#pragma unroll
    for (int i = 0; i < 4; ++i) {
      int idx = tid + 256 * i;
      int mr = idx >> 4, kk = idx & 15;
      As[kk][mr] = bf2f(A[(size_t)(m0 + mr) * 1024 + k0 + kk]);
    }
#pragma unroll
    for (int i = 0; i < 4; ++i) {
      int idx = tid + 256 * i;
      int kr = idx >> 6, nc = idx & 63;
      Bs[kr][nc] = W[(size_t)(k0 + kr) * 1024 + n0 + nc];
    }
    __syncthreads();
#pragma unroll
    for (int kk = 0; kk < 16; ++kk) {
      float a[4], bb[4];
#pragma unroll
      for (int i = 0; i < 4; ++i) a[i] = As[kk][ty + 16 * i];
#pragma unroll
      for (int j = 0; j < 4; ++j) bb[j] = Bs[kk][tx + 16 * j];
#pragma unroll
      for (int i = 0; i < 4; ++i)
#pragma unroll
        for (int j = 0; j < 4; ++j) acc[i][j] += a[i] * bb[j];
    }
    __syncthreads();
  }
#pragma unroll
  for (int i = 0; i < 4; ++i) {
    int m = m0 + ty + 16 * i;
#pragma unroll
    for (int j = 0; j < 4; ++j) {
      int c = n0 + tx + 16 * j;
      out[(size_t)m * 1024 + c] = acc[i][j] + bias[c];
    }
  }
}

extern "C" void kernel_launch(void* const* d_in, const int* in_sizes, int n_in,
                              void* d_out, int out_size, void* d_ws, size_t ws_size,
                              hipStream_t stream) {
  const float* x        = (const float*)d_in[0];
  const float* time_emb = (const float*)d_in[1];
  const float* W_qkv    = (const float*)d_in[2];
  const float* b_qkv    = (const float*)d_in[3];
  const float* W_time   = (const float*)d_in[4];
  const float* b_time   = (const float*)d_in[5];
  const float* W_out    = (const float*)d_in[6];
  const float* b_out    = (const float*)d_in[7];
  const float* Er       = (const float*)d_in[8];
  float* out = (float*)d_out;

  char* base = (char*)d_ws;
  float* tqkv = (float*)base;                                   // 98304 B
  unsigned short* qb     = (unsigned short*)(base + 98304);     // 16 MB each
  unsigned short* kb     = qb + (size_t)8388608;
  unsigned short* vb     = kb + (size_t)8388608;
  unsigned short* attn_o = vb + (size_t)8388608;
  unsigned short* Er_bf  = attn_o + (size_t)8388608;            // 128 KB
  unsigned short* Gsk    = Er_bf + 65536;                       // 67 MB (slab)

  er_convert_kernel<<<256, 256, 0, stream>>>(Er, Er_bf);
  time_proj_kernel<<<96, 256, 0, stream>>>(time_emb, W_time, b_time, tqkv);
  qkv_gemm_kernel<<<dim3(128, 48), 256, 0, stream>>>(x, W_qkv, b_qkv, tqkv,
                                                     qb, kb, vb);
  for (int s = 0; s < 4; ++s) {
    int bh_base = s * SLAB_BH;
    g_gemm_kernel<<<dim3(16, 16, SLAB_BH), 256, 0, stream>>>(qb, bh_base, Er_bf, Gsk);
    diag_zero_kernel<<<(SLAB_BH * 1023 + 255) / 256, 256, 0, stream>>>(Gsk);
    attn_kernel<<<dim3(16, SLAB_BH), 256, 0, stream>>>(qb, kb, vb, Gsk, attn_o, bh_base);
  }
  out_gemm_kernel<<<dim3(128, 16), 256, 0, stream>>>(attn_o, W_out, b_out, out);
}

// Round 3
// 523.033 us; speedup vs baseline: 16.6737x; 2.9300x over previous
//
#include <hip/hip_runtime.h>
#include <math.h>

typedef __attribute__((ext_vector_type(8))) short short8;
typedef __attribute__((ext_vector_type(8))) unsigned short ushort8;
typedef __attribute__((ext_vector_type(4))) float f32x4;

#define NH 16
#define HD 64
#define SEQ 1024
#define NB 8
#define CH 1024
#define TD 256
#define SLAB_BH 32

__device__ __forceinline__ unsigned short f2bf(float f) {
  union { float f; unsigned int u; } v; v.f = f;
  unsigned int r = v.u + 0x7FFFu + ((v.u >> 16) & 1u);
  return (unsigned short)(r >> 16);
}
__device__ __forceinline__ float bf2f(unsigned short s) {
  union { unsigned int u; float f; } v; v.u = ((unsigned int)s) << 16;
  return v.f;
}
__device__ __forceinline__ void gload_lds16(const unsigned short* g, unsigned short* l) {
  __builtin_amdgcn_global_load_lds(
      (const __attribute__((address_space(1))) unsigned int*)g,
      (__attribute__((address_space(3))) unsigned int*)l, 16, 0, 0);
}

// ---------------- time projection (fp32) ----------------
__global__ __launch_bounds__(256) void time_proj_kernel(
    const float* __restrict__ time_emb, const float* __restrict__ W_time,
    const float* __restrict__ b_time, float* __restrict__ tqkv) {
  int idx = blockIdx.x * 256 + threadIdx.x;
  if (idx >= NB * 3072) return;
  int b = idx / 3072, c = idx % 3072;
  float s = b_time[c];
  for (int t = 0; t < TD; ++t) s += time_emb[b * TD + t] * W_time[t * 3072 + c];
  tqkv[idx] = s;
}

// ---------------- Er fp32 -> bf16 ----------------
__global__ __launch_bounds__(256) void er_convert_kernel(
    const float* __restrict__ Er, unsigned short* __restrict__ Er_bf) {
  int i = blockIdx.x * 256 + threadIdx.x;
  if (i < SEQ * HD) Er_bf[i] = f2bf(Er[i]);
}

// ---------------- fp32 -> bf16 vector convert ----------------
__global__ __launch_bounds__(256) void convert_bf_kernel(
    const float* __restrict__ in, unsigned short* __restrict__ out, int n8) {
  int i = blockIdx.x * 256 + threadIdx.x;
  if (i >= n8) return;
  float4 a = ((const float4*)in)[2 * i];
  float4 b = ((const float4*)in)[2 * i + 1];
  ushort8 o;
  o[0] = f2bf(a.x); o[1] = f2bf(a.y); o[2] = f2bf(a.z); o[3] = f2bf(a.w);
  o[4] = f2bf(b.x); o[5] = f2bf(b.y); o[6] = f2bf(b.z); o[7] = f2bf(b.w);
  ((ushort8*)out)[i] = o;
}

// ---------------- fp32 W[R][C] -> bf16 Wt[C][R] ----------------
__global__ __launch_bounds__(256) void transpose_bf_kernel(
    const float* __restrict__ W, unsigned short* __restrict__ Wt, int R, int Cc) {
  __shared__ float T[64][65];
  int r0 = blockIdx.y * 64, c0 = blockIdx.x * 64;
  for (int idx = threadIdx.x; idx < 4096; idx += 256) {
    int r = idx >> 6, c = idx & 63;
    T[r][c] = W[(size_t)(r0 + r) * Cc + c0 + c];
  }
  __syncthreads();
  for (int idx = threadIdx.x; idx < 4096; idx += 256) {
    int c = idx >> 6, r = idx & 63;
    Wt[(size_t)(c0 + c) * R + r0 + r] = f2bf(T[r][c]);
  }
}

// ---------------- QKV GEMM: bf16 MFMA, m97 structure ----------------
// A=x_bf[8192][1024], Bt=Wqkv_t[3072][1024]; out scatter to q/k/v + bias + tqkv
__global__ __launch_bounds__(256) void qkv_gemm_mfma(
    const unsigned short* __restrict__ A, const unsigned short* __restrict__ Bt,
    const float* __restrict__ bqkv, const float* __restrict__ tqkv,
    unsigned short* __restrict__ qb, unsigned short* __restrict__ kb,
    unsigned short* __restrict__ vb) {
  __shared__ unsigned short As[128 * 32];
  __shared__ unsigned short Bs[128 * 32];
  const int m0 = blockIdx.x * 128, n0 = blockIdx.y * 128;
  const int tid = threadIdx.x, l = tid & 63, w = tid >> 6;
  const int wm = w >> 1, wn = w & 1;
  const int grp = l >> 4, col = l & 15;
  f32x4 acc[4][4];
#pragma unroll
  for (int mi = 0; mi < 4; ++mi)
#pragma unroll
    for (int ni = 0; ni < 4; ++ni) acc[mi][ni] = (f32x4){0.f, 0.f, 0.f, 0.f};

  for (int k0 = 0; k0 < 1024; k0 += 32) {
    __syncthreads();
#pragma unroll
    for (int i = 0; i < 2; ++i) {
      int seg = i * 256 + w * 64 + l;
      int mr = seg >> 2, kq = seg & 3;
      gload_lds16(A + (size_t)(m0 + mr) * 1024 + k0 + kq * 8,
                  &As[(i * 256 + w * 64) * 8]);
      gload_lds16(Bt + (size_t)(n0 + mr) * 1024 + k0 + kq * 8,
                  &Bs[(i * 256 + w * 64) * 8]);
    }
    __syncthreads();
    short8 af[4], bfv[4];
#pragma unroll
    for (int mi = 0; mi < 4; ++mi)
      af[mi] = *(const short8*)&As[(wm * 64 + mi * 16 + col) * 32 + grp * 8];
#pragma unroll
    for (int ni = 0; ni < 4; ++ni)
      bfv[ni] = *(const short8*)&Bs[(wn * 64 + ni * 16 + col) * 32 + grp * 8];
#pragma unroll
    for (int mi = 0; mi < 4; ++mi)
#pragma unroll
      for (int ni = 0; ni < 4; ++ni)
        acc[mi][ni] = __builtin_amdgcn_mfma_f32_16x16x32_bf16(af[mi], bfv[ni], acc[mi][ni], 0, 0, 0);
  }

  const int bidx = m0 >> 10;
  const int which = n0 >> 10;
  unsigned short* dst = (which == 0) ? qb : (which == 1) ? kb : vb;
  float biasv[4];
  int hhv[4], dv[4];
#pragma unroll
  for (int ni = 0; ni < 4; ++ni) {
    int c = n0 + wn * 64 + ni * 16 + col;
    biasv[ni] = bqkv[c] + tqkv[bidx * 3072 + c];
    int cc = c & 1023;
    hhv[ni] = cc >> 6;
    dv[ni] = cc & 63;
  }
#pragma unroll
  for (int mi = 0; mi < 4; ++mi)
#pragma unroll
    for (int rr = 0; rr < 4; ++rr) {
      int row = m0 + wm * 64 + mi * 16 + grp * 4 + rr;
      int nn = row & 1023;
#pragma unroll
      for (int ni = 0; ni < 4; ++ni)
        dst[(((size_t)(bidx * 16 + hhv[ni])) * 1024 + nn) * 64 + dv[ni]] =
            f2bf(acc[mi][ni][rr] + biasv[ni]);
    }
}

// ---------------- output projection: bf16 MFMA ----------------
__global__ __launch_bounds__(256) void out_gemm_mfma(
    const unsigned short* __restrict__ A, const unsigned short* __restrict__ Bt,
    const float* __restrict__ bias, float* __restrict__ out) {
  __shared__ unsigned short As[128 * 32];
  __shared__ unsigned short Bs[128 * 32];
  const int m0 = blockIdx.x * 128, n0 = blockIdx.y * 128;
  const int tid = threadIdx.x, l = tid & 63, w = tid >> 6;
  const int wm = w >> 1, wn = w & 1;
  const int grp = l >> 4, col = l & 15;
  f32x4 acc[4][4];
#pragma unroll
  for (int mi = 0; mi < 4; ++mi)
#pragma unroll
    for (int ni = 0; ni < 4; ++ni) acc[mi][ni] = (f32x4){0.f, 0.f, 0.f, 0.f};

  for (int k0 = 0; k0 < 1024; k0 += 32) {
    __syncthreads();
#pragma unroll
    for (int i = 0; i < 2; ++i) {
      int seg = i * 256 + w * 64 + l;
      int mr = seg >> 2, kq = seg & 3;
      gload_lds16(A + (size_t)(m0 + mr) * 1024 + k0 + kq * 8,
                  &As[(i * 256 + w * 64) * 8]);
      gload_lds16(Bt + (size_t)(n0 + mr) * 1024 + k0 + kq * 8,
                  &Bs[(i * 256 + w * 64) * 8]);
    }
    __syncthreads();
    short8 af[4], bfv[4];
#pragma unroll
    for (int mi = 0; mi < 4; ++mi)
      af[mi] = *(const short8*)&As[(wm * 64 + mi * 16 + col) * 32 + grp * 8];
#pragma unroll
    for (int ni = 0; ni < 4; ++ni)
      bfv[ni] = *(const short8*)&Bs[(wn * 64 + ni * 16 + col) * 32 + grp * 8];
#pragma unroll
    for (int mi = 0; mi < 4; ++mi)
#pragma unroll
      for (int ni = 0; ni < 4; ++ni)
        acc[mi][ni] = __builtin_amdgcn_mfma_f32_16x16x32_bf16(af[mi], bfv[ni], acc[mi][ni], 0, 0, 0);
  }
  float bv[4];
#pragma unroll
  for (int ni = 0; ni < 4; ++ni) bv[ni] = bias[n0 + wn * 64 + ni * 16 + col];
#pragma unroll
  for (int mi = 0; mi < 4; ++mi)
#pragma unroll
    for (int rr = 0; rr < 4; ++rr) {
      int row = m0 + wm * 64 + mi * 16 + grp * 4 + rr;
#pragma unroll
      for (int ni = 0; ni < 4; ++ni) {
        int c = n0 + wn * 64 + ni * 16 + col;
        out[(size_t)row * 1024 + c] = acc[mi][ni][rr] + bv[ni];
      }
    }
}

// ---------------- G GEMM with skew remap store ----------------
// G[n][j] = q_n . Er[j]; store to Gsk[n][j+n-1023] (j>=1023-n) else Gsk[n-1][j+n+1]
// Position (n, n+1) is never written (the skew's dropped pad element) -> masked in attn.
__global__ __launch_bounds__(256) void g_gemm_kernel(
    const unsigned short* __restrict__ qb, int bh_base,
    const unsigned short* __restrict__ Er_bf,
    unsigned short* __restrict__ Gsk) {
  const int n0 = blockIdx.x * 64, j0 = blockIdx.y * 64, bhl = blockIdx.z;
  const int bh = bh_base + bhl;
  const int tid = threadIdx.x, lane = tid & 63, wq = tid >> 6;
  const int grp = lane >> 4, col = lane & 15;
  short8 aq[2];
  const int nrow = n0 + wq * 16 + col;
#pragma unroll
  for (int dc = 0; dc < 2; ++dc)
    aq[dc] = *(const short8*)(qb + ((size_t)(bh * SEQ + nrow)) * HD + dc * 32 + grp * 8);
  f32x4 acc[4];
#pragma unroll
  for (int mc = 0; mc < 4; ++mc) acc[mc] = (f32x4){0.f, 0.f, 0.f, 0.f};
#pragma unroll
  for (int mc = 0; mc < 4; ++mc)
#pragma unroll
    for (int dc = 0; dc < 2; ++dc) {
      short8 bfrag = *(const short8*)(Er_bf + (size_t)(j0 + mc * 16 + col) * HD + dc * 32 + grp * 8);
      acc[mc] = __builtin_amdgcn_mfma_f32_16x16x32_bf16(aq[dc], bfrag, acc[mc], 0, 0, 0);
    }
#pragma unroll
  for (int mc = 0; mc < 4; ++mc)
#pragma unroll
    for (int r = 0; r < 4; ++r) {
      int n = n0 + wq * 16 + grp * 4 + r;
      int j = j0 + mc * 16 + col;
      float val = acc[mc][r];
      int tr, tm;
      if (j >= 1023 - n) { tr = n; tm = j + n - 1023; }
      else               { tr = n - 1; tm = j + n + 1; }
      if (tr >= 0) Gsk[((size_t)(bhl * SEQ + tr) << 10) + tm] = f2bf(val);
    }
}

// ---------------- flash attention, bf16 MFMA ----------------
__global__ __launch_bounds__(256) void attn_kernel(
    const unsigned short* __restrict__ qb, const unsigned short* __restrict__ kb,
    const unsigned short* __restrict__ vb, const unsigned short* __restrict__ Gsk,
    unsigned short* __restrict__ attn_o, int bh_base) {
  __shared__ __align__(16) unsigned short Ks[64][72];
  __shared__ __align__(16) unsigned short Vt[64][72];
  __shared__ __align__(16) unsigned short Pw[4][16][72];
  const int n0 = blockIdx.x * 64;
  const int bhl = blockIdx.y;
  const int bh = bh_base + bhl;
  const int b = bh >> 4, h = bh & 15;
  const int tid = threadIdx.x, lane = tid & 63, wq = tid >> 6;
  const int grp = lane >> 4, col = lane & 15;
  const int n0w = n0 + wq * 16;

  short8 aq[2];
#pragma unroll
  for (int dc = 0; dc < 2; ++dc)
    aq[dc] = *(const short8*)(qb + ((size_t)(bh * SEQ + n0w + col)) * HD + dc * 32 + grp * 8);

  f32x4 acco[4];
#pragma unroll
  for (int oc = 0; oc < 4; ++oc) acco[oc] = (f32x4){0.f, 0.f, 0.f, 0.f};
  float mrun[4], lrun[4];
#pragma unroll
  for (int r = 0; r < 4; ++r) { mrun[r] = -INFINITY; lrun[r] = 0.f; }

  unsigned short gv[16];
  const size_t grow = ((size_t)(bhl * SEQ + n0w + grp * 4)) << 10;
#pragma unroll
  for (int r = 0; r < 4; ++r)
#pragma unroll
    for (int mc = 0; mc < 4; ++mc)
      gv[r * 4 + mc] = Gsk[grow + ((size_t)r << 10) + mc * 16 + col];

  const float scale = 0.125f;
  const unsigned short* kbh = kb + (size_t)bh * SEQ * HD;
  const unsigned short* vbh = vb + (size_t)bh * SEQ * HD;

  for (int m0 = 0; m0 < SEQ; m0 += 64) {
    __syncthreads();
    {
      int rowa = tid >> 3;
      int d0 = (tid & 7) * 8;
#pragma unroll
      for (int it = 0; it < 2; ++it) {
        int m = rowa + it * 32;
        short8 kv = *(const short8*)(kbh + (size_t)(m0 + m) * HD + d0);
        *(short8*)&Ks[m][d0] = kv;
        short8 vv = *(const short8*)(vbh + (size_t)(m0 + m) * HD + d0);
#pragma unroll
        for (int e = 0; e < 8; ++e) Vt[d0 + e][m] = (unsigned short)vv[e];
      }
    }
    __syncthreads();
    f32x4 acc[4];
#pragma unroll
    for (int mc = 0; mc < 4; ++mc) acc[mc] = (f32x4){0.f, 0.f, 0.f, 0.f};
#pragma unroll
    for (int mc = 0; mc < 4; ++mc)
#pragma unroll
      for (int dc = 0; dc < 2; ++dc) {
        short8 bk = *(const short8*)&Ks[mc * 16 + col][dc * 32 + grp * 8];
        acc[mc] = __builtin_amdgcn_mfma_f32_16x16x32_bf16(aq[dc], bk, acc[mc], 0, 0, 0);
      }
    float gf[16];
#pragma unroll
    for (int i = 0; i < 16; ++i) gf[i] = bf2f(gv[i]);
    if (m0 + 64 < SEQ) {
#pragma unroll
      for (int r = 0; r < 4; ++r)
#pragma unroll
        for (int mc = 0; mc < 4; ++mc)
          gv[r * 4 + mc] = Gsk[grow + ((size_t)r << 10) + (m0 + 64) + mc * 16 + col];
    }
#pragma unroll
    for (int r = 0; r < 4; ++r) {
      int n = n0w + grp * 4 + r;
      float s[4];
#pragma unroll
      for (int mc = 0; mc < 4; ++mc) {
        float g = gf[r * 4 + mc];
        int m = m0 + mc * 16 + col;
        if (m == n + 1) g = 0.f;  // skew's dropped-pad diagonal
        s[mc] = acc[mc][r] * scale + g;
      }
      float mx = fmaxf(fmaxf(s[0], s[1]), fmaxf(s[2], s[3]));
#pragma unroll
      for (int off = 1; off < 16; off <<= 1) mx = fmaxf(mx, __shfl_xor(mx, off));
      float mnew = fmaxf(mrun[r], mx);
      float cr = __expf(mrun[r] - mnew);
      float ls = 0.f;
      float p[4];
#pragma unroll
      for (int mc = 0; mc < 4; ++mc) { p[mc] = __expf(s[mc] - mnew); ls += p[mc]; }
#pragma unroll
      for (int off = 1; off < 16; off <<= 1) ls += __shfl_xor(ls, off);
      lrun[r] = lrun[r] * cr + ls;
      mrun[r] = mnew;
#pragma unroll
      for (int oc = 0; oc < 4; ++oc) acco[oc][r] *= cr;
#pragma unroll
      for (int mc = 0; mc < 4; ++mc) Pw[wq][grp * 4 + r][mc * 16 + col] = f2bf(p[mc]);
    }
    short8 ap[2];
#pragma unroll
    for (int kc = 0; kc < 2; ++kc)
      ap[kc] = *(const short8*)&Pw[wq][col][kc * 32 + grp * 8];
#pragma unroll
    for (int oc = 0; oc < 4; ++oc)
#pragma unroll
      for (int kc = 0; kc < 2; ++kc) {
        short8 bv = *(const short8*)&Vt[oc * 16 + col][kc * 32 + grp * 8];
        acco[oc] = __builtin_amdgcn_mfma_f32_16x16x32_bf16(ap[kc], bv, acco[oc], 0, 0, 0);
      }
  }
#pragma unroll
  for (int oc = 0; oc < 4; ++oc)
#pragma unroll
    for (int r = 0; r < 4; ++r) {
      int n = n0w + grp * 4 + r;
      int d = oc * 16 + col;
      attn_o[((size_t)(b * SEQ + n)) * CH + h * HD + d] = f2bf(acco[oc][r] / lrun[r]);
    }
}

extern "C" void kernel_launch(void* const* d_in, const int* in_sizes, int n_in,
                              void* d_out, int out_size, void* d_ws, size_t ws_size,
                              hipStream_t stream) {
  const float* x        = (const float*)d_in[0];
  const float* time_emb = (const float*)d_in[1];
  const float* W_qkv    = (const float*)d_in[2];
  const float* b_qkv    = (const float*)d_in[3];
  const float* W_time   = (const float*)d_in[4];
  const float* b_time   = (const float*)d_in[5];
  const float* W_out    = (const float*)d_in[6];
  const float* b_out    = (const float*)d_in[7];
  const float* Er       = (const float*)d_in[8];
  float* out = (float*)d_out;

  char* p = (char*)d_ws;
  float* tqkv = (float*)p;                      p += 98304;
  unsigned short* qb = (unsigned short*)p;      p += 16777216;
  unsigned short* kb = (unsigned short*)p;      p += 16777216;
  unsigned short* vb = (unsigned short*)p;      p += 16777216;
  unsigned short* attn_o = (unsigned short*)p;  p += 16777216;
  unsigned short* Er_bf = (unsigned short*)p;   p += 131072;
  unsigned short* Wout_t = (unsigned short*)p;  p += 2097152;
  unsigned short* x_bf = (unsigned short*)p;               // 16 MB
  unsigned short* Wqkv_t = x_bf + (size_t)8388608;         // 6 MB
  unsigned short* Gsk = (unsigned short*)p;                // 67 MB, aliases x_bf (dead)

  er_convert_kernel<<<256, 256, 0, stream>>>(Er, Er_bf);
  time_proj_kernel<<<96, 256, 0, stream>>>(time_emb, W_time, b_time, tqkv);
  convert_bf_kernel<<<4096, 256, 0, stream>>>(x, x_bf, 1048576);
  transpose_bf_kernel<<<dim3(48, 16), 256, 0, stream>>>(W_qkv, Wqkv_t, 1024, 3072);
  transpose_bf_kernel<<<dim3(16, 16), 256, 0, stream>>>(W_out, Wout_t, 1024, 1024);
  qkv_gemm_mfma<<<dim3(64, 24), 256, 0, stream>>>(x_bf, Wqkv_t, b_qkv, tqkv, qb, kb, vb);
  for (int s = 0; s < 4; ++s) {
    int bh_base = s * SLAB_BH;
    g_gemm_kernel<<<dim3(16, 16, SLAB_BH), 256, 0, stream>>>(qb, bh_base, Er_bf, Gsk);
    attn_kernel<<<dim3(16, SLAB_BH), 256, 0, stream>>>(qb, kb, vb, Gsk, attn_o, bh_base);
  }
  out_gemm_mfma<<<dim3(64, 8), 256, 0, stream>>>(attn_o, Wout_t, b_out, out);
}